// Round 16
// baseline (733.040 us; speedup 1.0000x reference)
//
#include <hip/hip_runtime.h>

#define NNODES 50000
#define NEDGES 800000
#define ET (NEDGES + NNODES)   // 850000 edges incl. self loops
#define HEADS 4

typedef __attribute__((ext_vector_type(8))) short bf16x8;
typedef __attribute__((ext_vector_type(4))) float f32x4;
typedef __attribute__((ext_vector_type(2))) float f32x2v;

#define EXP2F(x) __builtin_amdgcn_exp2f(x)

#if defined(__has_builtin)
#if __has_builtin(__builtin_elementwise_fma)
#define VFMA(a, b, c) __builtin_elementwise_fma((a), (b), (c))
#endif
#if __has_builtin(__builtin_elementwise_max)
#define VMAX(a, b) __builtin_elementwise_max((a), (b))
#endif
#endif
#ifndef VFMA
__device__ inline f32x2v vfma_(f32x2v a, f32x2v b, f32x2v c) {
  f32x2v r; r.x = fmaf(a.x, b.x, c.x); r.y = fmaf(a.y, b.y, c.y); return r;
}
#define VFMA vfma_
#endif
#ifndef VMAX
__device__ inline f32x2v vmax_(f32x2v a, f32x2v b) {
  f32x2v r; r.x = fmaxf(a.x, b.x); r.y = fmaxf(a.y, b.y); return r;
}
#define VMAX vmax_
#endif

#define GLOAD16(g, l) __builtin_amdgcn_global_load_lds(                      \
    (const __attribute__((address_space(1))) unsigned int*)(g),              \
    (__attribute__((address_space(3))) unsigned int*)(l), 16, 0, 0)

__device__ inline unsigned short f2bf(float f) {
  union { float f; unsigned int i; } c; c.f = f;
  unsigned int b = c.i + 0x7fffu + ((c.i >> 16) & 1u);   // RTN-even
  return (unsigned short)(b >> 16);
}
__device__ inline f32x2v cvtpair(unsigned u) {
  union { unsigned i; float f; } lo, hi;
  lo.i = u << 16; hi.i = u & 0xffff0000u;
  f32x2v r; r.x = lo.f; r.y = hi.f; return r;
}

// ---------------- merged prep: cast x -> bf16 | edge histogram | weight transpose ----

#define CASTB 25000
#define HISTB ((ET + 255) / 256)
#define PREPB (CASTB + HISTB + 512)

__global__ __launch_bounds__(256) void k_prep(
    const int* __restrict__ ei, int* __restrict__ deg,
    const float* __restrict__ x, unsigned short* __restrict__ xb,
    const float* __restrict__ W1l, const float* __restrict__ W1r,
    const float* __restrict__ W2l, const float* __restrict__ W2r,
    unsigned short* __restrict__ w1t, unsigned short* __restrict__ w2t) {
  __shared__ float tile[32][33];
  int b = blockIdx.x;
  if (b < CASTB) {
    int i = b * 256 + threadIdx.x;
    float4 v = ((const float4*)x)[i];
    ushort4 o;
    o.x = f2bf(v.x); o.y = f2bf(v.y); o.z = f2bf(v.z); o.w = f2bf(v.w);
    ((ushort4*)xb)[i] = o;
  } else if (b < CASTB + HISTB) {
    int i = (b - CASTB) * 256 + threadIdx.x;
    if (i < ET) {
      int dst = (i < NEDGES) ? ei[NEDGES + i] : (i - NEDGES);
      atomicAdd(&deg[dst], 1);
    }
  } else {
    int bb = b - CASTB - HISTB;
    int which = bb >> 7, bx = bb & 127;
    const float* W;
    unsigned short* T;
    int K, N, noff;
    if (which == 0)      { W = W1l; T = w1t; K = 512; N = 256; noff = 0; }
    else if (which == 1) { W = W1r; T = w1t; K = 512; N = 256; noff = 256; }
    else if (which == 2) { W = W2l; T = w2t; K = 256; N = 512; noff = 0; }
    else                 { W = W2r; T = w2t; K = 256; N = 512; noff = 512; }
    int tpr = N >> 5;
    int tk = (bx / tpr) << 5;
    int tn = (bx % tpr) << 5;
    int c = threadIdx.x & 31, r = threadIdx.x >> 5;
#pragma unroll
    for (int rr = 0; rr < 32; rr += 8)
      tile[r + rr][c] = W[(size_t)(tk + r + rr) * N + tn + c];
    __syncthreads();
#pragma unroll
    for (int rr = 0; rr < 32; rr += 8)
      T[(size_t)(tn + r + rr + noff) * K + tk + c] = f2bf(tile[c][r + rr]);
  }
}

// ---------------- CSR scan/scatter ----------------

__global__ void k_scan1(const int* __restrict__ deg, int* __restrict__ part,
                        int* __restrict__ bsum, int n) {
  __shared__ int s[256];
  int tid = threadIdx.x;
  int i = blockIdx.x * 256 + tid;
  int v = (i < n) ? deg[i] : 0;
  s[tid] = v;
  __syncthreads();
  for (int off = 1; off < 256; off <<= 1) {
    int t = (tid >= off) ? s[tid - off] : 0;
    __syncthreads();
    s[tid] += t;
    __syncthreads();
  }
  if (i < n) part[i] = s[tid] - v;
  if (tid == 255) bsum[blockIdx.x] = s[255];
}

__global__ void k_scan2(int* bsum, int nb) {
  __shared__ int s[256];
  int t = threadIdx.x;
  int v = (t < nb) ? bsum[t] : 0;
  s[t] = v;
  __syncthreads();
  for (int off = 1; off < 256; off <<= 1) {
    int tv = (t >= off) ? s[t - off] : 0;
    __syncthreads();
    s[t] += tv;
    __syncthreads();
  }
  if (t < nb) bsum[t] = s[t] - v;
}

__global__ void k_scan3(const int* __restrict__ part, const int* __restrict__ bsum,
                        int* __restrict__ rowstart, int* __restrict__ cursor,
                        int n, int total) {
  int i = blockIdx.x * blockDim.x + threadIdx.x;
  if (i < n) {
    int v = part[i] + bsum[i >> 8];
    rowstart[i] = v;
    cursor[i] = v;
  }
  if (i == n) rowstart[n] = total;
}

__global__ void k_scatter(const int* __restrict__ ei, int* __restrict__ cursor,
                          int* __restrict__ csrsrc) {
  int i = blockIdx.x * blockDim.x + threadIdx.x;
  if (i >= ET) return;
  int src, dst;
  if (i < NEDGES) { src = ei[i]; dst = ei[NEDGES + i]; }
  else            { src = dst = i - NEDGES; }
  int pos = atomicAdd(&cursor[dst], 1);
  csrsrc[pos] = src;
}

// ---------------- degree-sorted permutation (counting sort, 1024 bins) ----------

__global__ void k_dbin(const int* __restrict__ deg, int* __restrict__ dbin) {
  int i = blockIdx.x * blockDim.x + threadIdx.x;
  if (i < NNODES) atomicAdd(&dbin[min(deg[i], 1023)], 1);
}

__global__ void k_dscan(int* __restrict__ dbin) {   // inclusive->exclusive in place
  __shared__ int s[1024];
  int t = threadIdx.x;
  int o[4];
#pragma unroll
  for (int k = 0; k < 4; ++k) { o[k] = dbin[t * 4 + k]; s[t * 4 + k] = o[k]; }
  __syncthreads();
  for (int off = 1; off < 1024; off <<= 1) {
    int v[4];
#pragma unroll
    for (int k = 0; k < 4; ++k) {
      int j = t * 4 + k;
      v[k] = (j >= off) ? s[j - off] : 0;
    }
    __syncthreads();
#pragma unroll
    for (int k = 0; k < 4; ++k) s[t * 4 + k] += v[k];
    __syncthreads();
  }
#pragma unroll
  for (int k = 0; k < 4; ++k) dbin[t * 4 + k] = s[t * 4 + k] - o[k];  // exclusive
}

__global__ void k_dscat(const int* __restrict__ deg, int* __restrict__ dbin,
                        int* __restrict__ perm) {
  int i = blockIdx.x * blockDim.x + threadIdx.x;
  if (i >= NNODES) return;
  int pos = atomicAdd(&dbin[min(deg[i], 1023)], 1);
  perm[pos] = i;
}

// ---------------- bf16 MFMA GEMM, 3-buffer counted-vmcnt pipeline (T4) ----------

template <int N> __device__ __forceinline__ void waitvm() {
  if constexpr (N == 0) asm volatile("s_waitcnt vmcnt(0)" ::: "memory");
  else if constexpr (N == 4) asm volatile("s_waitcnt vmcnt(4)" ::: "memory");
  else asm volatile("s_waitcnt vmcnt(8)" ::: "memory");
}

__global__ __launch_bounds__(256) void k_gemm(
    const unsigned short* __restrict__ A, const unsigned short* __restrict__ Bt,
    const float* __restrict__ bL, const float* __restrict__ bR, int nsplit,
    unsigned short* __restrict__ C, int M, int K, int N) {
  __shared__ unsigned short As[3][128 * 32];
  __shared__ unsigned short Bs[3][128 * 32];
  int tid = threadIdx.x;
  int lane = tid & 63, wave = tid >> 6;
  int wr = (wave >> 1) * 64, wc = (wave & 1) * 64;
  int row0 = blockIdx.x * 128, col0 = blockIdx.y * 128;
  int fr = lane & 15, fq = lane >> 4;
  int sr = tid >> 2, sc = (tid & 3) * 8;

  const unsigned short* ga0 = &A[(size_t)(row0 + sr) * K + sc];
  const unsigned short* ga1 = &A[(size_t)(row0 + sr + 64) * K + sc];
  const unsigned short* gb0 = &Bt[(size_t)(col0 + sr) * K + sc];
  const unsigned short* gb1 = &Bt[(size_t)(col0 + sr + 64) * K + sc];

  f32x4 acc[4][4] = {};
  const int NT = K >> 5;

#define STAGE(b, k0)                                  \
  do {                                                \
    GLOAD16(ga0 + (k0), &As[b][tid * 8]);             \
    GLOAD16(ga1 + (k0), &As[b][2048 + tid * 8]);      \
    GLOAD16(gb0 + (k0), &Bs[b][tid * 8]);             \
    GLOAD16(gb1 + (k0), &Bs[b][2048 + tid * 8]);      \
  } while (0)

#define COMPUTE(b)                                                        \
  do {                                                                    \
    bf16x8 af[4], bfr[4];                                                 \
    _Pragma("unroll")                                                     \
    for (int m = 0; m < 4; ++m)                                           \
      af[m] = *(const bf16x8*)&As[b][(wr + m * 16 + fr) * 32 + fq * 8];   \
    _Pragma("unroll")                                                     \
    for (int n = 0; n < 4; ++n)                                           \
      bfr[n] = *(const bf16x8*)&Bs[b][(wc + n * 16 + fr) * 32 + fq * 8];  \
    _Pragma("unroll")                                                     \
    for (int m = 0; m < 4; ++m)                                           \
      _Pragma("unroll")                                                   \
      for (int n = 0; n < 4; ++n)                                         \
        acc[m][n] = __builtin_amdgcn_mfma_f32_16x16x32_bf16(af[m], bfr[n], acc[m][n], 0, 0, 0); \
  } while (0)

  STAGE(0, 0);
  STAGE(1, 32);
  STAGE(2, 64);

  for (int t = 0; t < NT - 3; ++t) {
    int b = t % 3;
    waitvm<8>();
    __builtin_amdgcn_s_barrier();
    COMPUTE(b);
    asm volatile("s_waitcnt lgkmcnt(0)" ::: "memory");
    __builtin_amdgcn_sched_barrier(0);
    __builtin_amdgcn_s_barrier();
    STAGE(b, (t + 3) << 5);
  }
  waitvm<8>(); __builtin_amdgcn_s_barrier(); COMPUTE((NT - 3) % 3);
  waitvm<4>(); __builtin_amdgcn_s_barrier(); COMPUTE((NT - 2) % 3);
  waitvm<0>(); __builtin_amdgcn_s_barrier(); COMPUTE((NT - 1) % 3);

#undef STAGE
#undef COMPUTE

#pragma unroll
  for (int m = 0; m < 4; ++m) {
#pragma unroll
    for (int n = 0; n < 4; ++n) {
      int col = col0 + wc + n * 16 + fr;
      float bv = (col < nsplit) ? bL[col] : bR[col - nsplit];
#pragma unroll
      for (int j = 0; j < 4; ++j) {
        int row = row0 + wr + m * 16 + fq * 4 + j;
        if (row < M) C[(size_t)row * N + col] = f2bf(acc[m][n][j] + bv);
      }
    }
  }
}

// ---------------- fused score + softmax + aggregate (R14 structure + perm) -------
// One wave per PERMUTED dst (degree-sorted -> intra-block balance).
// 16 lanes/head; lane covers CHL=CQ*4 contiguous channels. Packed-f32 math.
// exp2-domain softmax, no max tracking (|p|<~15 by construction). 4-edge unroll.

template <int CQ> struct raw_t;
template <> struct raw_t<1> { using T = uint2; };
template <> struct raw_t<2> { using T = uint4; };

template <int CQ>
__device__ __forceinline__ void unpackP(const typename raw_t<CQ>::T& r, f32x2v* x) {
  x[0] = cvtpair(r.x); x[1] = cvtpair(r.y);
  if constexpr (CQ == 2) { x[2] = cvtpair(r.z); x[3] = cvtpair(r.w); }
}

template <int CQ>
__device__ __forceinline__ float edge_score_pk(const f32x2v* x, const f32x2v* xr2,
                                               const f32x2v* att2) {
  const f32x2v c02 = {0.2f, 0.2f};
  f32x2v p2 = {0.f, 0.f};
#pragma unroll
  for (int j = 0; j < CQ * 2; ++j) {
    f32x2v s = x[j] + xr2[j];
    f32x2v g = VMAX(s, s * c02);
    p2 = VFMA(att2[j], g, p2);
  }
  return p2.x + p2.y;
}

template <int CQ, int MODE, int STR>
__global__ __launch_bounds__(256) void k_fused(
    const int* __restrict__ rowstart, const int* __restrict__ csrsrc,
    const int* __restrict__ perm,
    const unsigned short* __restrict__ xlr,
    const float* __restrict__ att, const float* __restrict__ bias,
    void* __restrict__ outp) {
  const int C = CQ * 64;
  const int CHL = CQ * 4;
  const int P = CQ * 2;
  using RawT = typename raw_t<CQ>::T;
  int wid = (blockIdx.x * blockDim.x + threadIdx.x) >> 6;
  int lane = threadIdx.x & 63;
  if (wid >= NNODES) return;
  int dst = __builtin_amdgcn_readfirstlane(perm[wid]);
  int h = lane >> 4;
  int l = lane & 15;
  const int choff = h * C + l * CHL;

  f32x2v xr2[P], att2[P];
  {
    RawT xrr = *(const RawT*)&xlr[(size_t)dst * STR + STR / 2 + choff];
    unpackP<CQ>(xrr, xr2);
#pragma unroll
    for (int j = 0; j < P; ++j) {
      att2[j].x = att[choff + j * 2 + 0] * 1.44269504f;
      att2[j].y = att[choff + j * 2 + 1] * 1.44269504f;
    }
  }

  int rs = __builtin_amdgcn_readfirstlane(rowstart[dst]);
  int re = __builtin_amdgcn_readfirstlane(rowstart[dst + 1]);

  float den = 0.f;
  f32x2v acc2[P];
#pragma unroll
  for (int j = 0; j < P; ++j) acc2[j] = (f32x2v){0.f, 0.f};

  int i = rs;
  for (; i + 4 <= re; i += 4) {
    int s0 = csrsrc[i + 0];
    int s1 = csrsrc[i + 1];
    int s2 = csrsrc[i + 2];
    int s3 = csrsrc[i + 3];
    RawT r0 = *(const RawT*)&xlr[(unsigned)s0 * (unsigned)STR + choff];
    RawT r1 = *(const RawT*)&xlr[(unsigned)s1 * (unsigned)STR + choff];
    RawT r2 = *(const RawT*)&xlr[(unsigned)s2 * (unsigned)STR + choff];
    RawT r3 = *(const RawT*)&xlr[(unsigned)s3 * (unsigned)STR + choff];
    f32x2v x0[P], x1[P], x2[P], x3[P];
    unpackP<CQ>(r0, x0); unpackP<CQ>(r1, x1);
    unpackP<CQ>(r2, x2); unpackP<CQ>(r3, x3);
    float p0 = edge_score_pk<CQ>(x0, xr2, att2);
    float p1 = edge_score_pk<CQ>(x1, xr2, att2);
    float p2 = edge_score_pk<CQ>(x2, xr2, att2);
    float p3 = edge_score_pk<CQ>(x3, xr2, att2);
#pragma unroll
    for (int d = 1; d <= 8; d <<= 1) {
      p0 += __shfl_xor(p0, d);
      p1 += __shfl_xor(p1, d);
      p2 += __shfl_xor(p2, d);
      p3 += __shfl_xor(p3, d);
    }
    float w0 = EXP2F(p0), w1 = EXP2F(p1), w2 = EXP2F(p2), w3 = EXP2F(p3);
    den += (w0 + w1) + (w2 + w3);
    f32x2v w0v = {w0, w0}, w1v = {w1, w1}, w2v = {w2, w2}, w3v = {w3, w3};
#pragma unroll
    for (int j = 0; j < P; ++j) {
      f32x2v a = acc2[j];
      a = VFMA(w0v, x0[j], a);
      a = VFMA(w1v, x1[j], a);
      a = VFMA(w2v, x2[j], a);
      a = VFMA(w3v, x3[j], a);
      acc2[j] = a;
    }
  }
  for (; i < re; ++i) {
    int s0 = csrsrc[i];
    RawT r0 = *(const RawT*)&xlr[(unsigned)s0 * (unsigned)STR + choff];
    f32x2v x0[P];
    unpackP<CQ>(r0, x0);
    float p0 = edge_score_pk<CQ>(x0, xr2, att2);
#pragma unroll
    for (int d = 1; d <= 8; d <<= 1) p0 += __shfl_xor(p0, d);
    float w0 = EXP2F(p0);
    den += w0;
    f32x2v wv = {w0, w0};
#pragma unroll
    for (int j = 0; j < P; ++j) acc2[j] = VFMA(wv, x0[j], acc2[j]);
  }

  float inv = 1.f / (den + 1e-16f);

  if (MODE == 0) {
    unsigned short* out = (unsigned short*)outp;
#pragma unroll
    for (int q = 0; q < CQ; ++q) {
      const float4 bv = *(const float4*)&bias[choff + q * 4];
      ushort4 o;
      o.x = f2bf(fmaxf(acc2[q * 2 + 0].x * inv + bv.x, 0.f));
      o.y = f2bf(fmaxf(acc2[q * 2 + 0].y * inv + bv.y, 0.f));
      o.z = f2bf(fmaxf(acc2[q * 2 + 1].x * inv + bv.z, 0.f));
      o.w = f2bf(fmaxf(acc2[q * 2 + 1].y * inv + bv.w, 0.f));
      *(ushort4*)&out[(size_t)dst * (HEADS * C) + choff + q * 4] = o;
    }
  } else {
    float* out = (float*)outp;
    float rr[8];   // CHL <= 8
#pragma unroll
    for (int j = 0; j < P; ++j) {
      rr[j * 2 + 0] = acc2[j].x * inv;
      rr[j * 2 + 1] = acc2[j].y * inv;
    }
#pragma unroll
    for (int c = 0; c < CHL; ++c) {
      rr[c] += __shfl_xor(rr[c], 16);   // sum across heads
      rr[c] += __shfl_xor(rr[c], 32);
    }
    if (lane < 16) {
#pragma unroll
      for (int q = 0; q < CQ; ++q) {
        int c = lane * CHL + q * 4;
        float4 o;
        o.x = rr[q * 4 + 0] * 0.25f + bias[c + 0];
        o.y = rr[q * 4 + 1] * 0.25f + bias[c + 1];
        o.z = rr[q * 4 + 2] * 0.25f + bias[c + 2];
        o.w = rr[q * 4 + 3] * 0.25f + bias[c + 3];
        *(float4*)&out[(size_t)dst * C + c] = o;
      }
    }
  }
}

// ---------------- orchestration ----------------

extern "C" void kernel_launch(void* const* d_in, const int* in_sizes, int n_in,
                              void* d_out, int out_size, void* d_ws, size_t ws_size,
                              hipStream_t stream) {
  (void)in_sizes; (void)n_in; (void)out_size; (void)ws_size;
  const float* x     = (const float*)d_in[0];
  const int*   ei    = (const int*)d_in[1];
  const float* W1l   = (const float*)d_in[2];
  const float* b1l   = (const float*)d_in[3];
  const float* W1r   = (const float*)d_in[4];
  const float* b1r   = (const float*)d_in[5];
  const float* att1  = (const float*)d_in[6];
  const float* bias1 = (const float*)d_in[7];
  const float* W2l   = (const float*)d_in[8];
  const float* b2l   = (const float*)d_in[9];
  const float* W2r   = (const float*)d_in[10];
  const float* b2r   = (const float*)d_in[11];
  const float* att2  = (const float*)d_in[12];
  const float* bias2 = (const float*)d_in[13];
  float* out = (float*)d_out;

  char* ws = (char*)d_ws;
  size_t off = 0;
  auto alloc = [&](size_t bytes) {
    char* p = ws + off;
    off = (off + bytes + 255) & ~(size_t)255;
    return p;
  };
  int*  deg      = (int*)alloc((size_t)NNODES * 4);
  int*  part     = (int*)alloc((size_t)NNODES * 4);
  int*  bsum     = (int*)alloc(256 * 4);
  int*  rowstart = (int*)alloc((size_t)(NNODES + 1) * 4);
  int*  cursor   = (int*)alloc((size_t)NNODES * 4);
  int*  csrsrc   = (int*)alloc((size_t)(ET + 32) * 4);
  int*  dbin     = (int*)alloc(1024 * 4);
  int*  perm     = (int*)alloc((size_t)NNODES * 4);
  unsigned short* xb   = (unsigned short*)alloc((size_t)NNODES * 512 * 2);
  unsigned short* w1t  = (unsigned short*)alloc((size_t)512 * 512 * 2);
  unsigned short* w2t  = (unsigned short*)alloc((size_t)1024 * 256 * 2);
  unsigned short* xlr1 = (unsigned short*)alloc((size_t)NNODES * 512 * 2);
  unsigned short* hbuf = (unsigned short*)alloc((size_t)NNODES * 256 * 2);
  unsigned short* xlr2 = (unsigned short*)alloc((size_t)NNODES * 1024 * 2);
  (void)alloc(64 * 1024);   // tail pad for GEMM A-row overrun reads

  (void)hipMemsetAsync(deg, 0, (size_t)NNODES * 4, stream);
  (void)hipMemsetAsync(dbin, 0, 1024 * 4, stream);

  // prep: cast x | histogram | weight transpose (merged)
  k_prep<<<PREPB, 256, 0, stream>>>(ei, deg, x, xb, W1l, W1r, W2l, W2r, w1t, w2t);

  int nb = (NNODES + 255) / 256;
  k_scan1<<<nb, 256, 0, stream>>>(deg, part, bsum, NNODES);
  k_dbin<<<nb, 256, 0, stream>>>(deg, dbin);
  k_scan2<<<1, 256, 0, stream>>>(bsum, nb);
  k_dscan<<<1, 256, 0, stream>>>(dbin);
  k_scan3<<<(NNODES + 256) / 256, 256, 0, stream>>>(part, bsum, rowstart, cursor, NNODES, ET);
  k_dscat<<<nb, 256, 0, stream>>>(deg, dbin, perm);
  k_scatter<<<(ET + 255) / 256, 256, 0, stream>>>(ei, cursor, csrsrc);

  const int gridM = (NNODES + 127) / 128;   // 391
  const int gridFused = (NNODES + 3) / 4;   // 12500

  // Layer 1: combined [W1l|W1r], K=512, N=512
  k_gemm<<<dim3(gridM, 4), 256, 0, stream>>>(xb, w1t, b1l, b1r, 256, xlr1, NNODES, 512, 512);
  k_fused<1, 0, 512><<<gridFused, 256, 0, stream>>>(rowstart, csrsrc, perm, xlr1, att1, bias1, hbuf);

  // Layer 2: combined [W2l|W2r], K=256, N=1024
  k_gemm<<<dim3(gridM, 8), 256, 0, stream>>>(hbuf, w2t, b2l, b2r, 512, xlr2, NNODES, 256, 1024);
  k_fused<2, 1, 1024><<<gridFused, 256, 0, stream>>>(rowstart, csrsrc, perm, xlr2, att2, bias2, out);
}

// Round 17
// 446.166 us; speedup vs baseline: 1.6430x; 1.6430x over previous
//
#include <hip/hip_runtime.h>

#define NNODES 50000
#define NEDGES 800000
#define ET (NEDGES + NNODES)   // 850000 edges incl. self loops
#define HEADS 4

typedef __attribute__((ext_vector_type(8))) short bf16x8;
typedef __attribute__((ext_vector_type(4))) float f32x4;
typedef __attribute__((ext_vector_type(2))) float f32x2v;

#define EXP2F(x) __builtin_amdgcn_exp2f(x)

#if defined(__has_builtin)
#if __has_builtin(__builtin_elementwise_fma)
#define VFMA(a, b, c) __builtin_elementwise_fma((a), (b), (c))
#endif
#if __has_builtin(__builtin_elementwise_max)
#define VMAX(a, b) __builtin_elementwise_max((a), (b))
#endif
#endif
#ifndef VFMA
__device__ inline f32x2v vfma_(f32x2v a, f32x2v b, f32x2v c) {
  f32x2v r; r.x = fmaf(a.x, b.x, c.x); r.y = fmaf(a.y, b.y, c.y); return r;
}
#define VFMA vfma_
#endif
#ifndef VMAX
__device__ inline f32x2v vmax_(f32x2v a, f32x2v b) {
  f32x2v r; r.x = fmaxf(a.x, b.x); r.y = fmaxf(a.y, b.y); return r;
}
#define VMAX vmax_
#endif

#define GLOAD16(g, l) __builtin_amdgcn_global_load_lds(                      \
    (const __attribute__((address_space(1))) unsigned int*)(g),              \
    (__attribute__((address_space(3))) unsigned int*)(l), 16, 0, 0)

__device__ inline unsigned short f2bf(float f) {
  union { float f; unsigned int i; } c; c.f = f;
  unsigned int b = c.i + 0x7fffu + ((c.i >> 16) & 1u);   // RTN-even
  return (unsigned short)(b >> 16);
}
__device__ inline f32x2v cvtpair(unsigned u) {
  union { unsigned i; float f; } lo, hi;
  lo.i = u << 16; hi.i = u & 0xffff0000u;
  f32x2v r; r.x = lo.f; r.y = hi.f; return r;
}

// ---------------- merged prep: cast x -> bf16 | edge histogram | weight transpose ----

#define CASTB 25000
#define HISTB ((ET + 255) / 256)
#define PREPB (CASTB + HISTB + 512)

__global__ __launch_bounds__(256) void k_prep(
    const int* __restrict__ ei, int* __restrict__ deg,
    const float* __restrict__ x, unsigned short* __restrict__ xb,
    const float* __restrict__ W1l, const float* __restrict__ W1r,
    const float* __restrict__ W2l, const float* __restrict__ W2r,
    unsigned short* __restrict__ w1t, unsigned short* __restrict__ w2t) {
  __shared__ float tile[32][33];
  int b = blockIdx.x;
  if (b < CASTB) {
    int i = b * 256 + threadIdx.x;
    float4 v = ((const float4*)x)[i];
    ushort4 o;
    o.x = f2bf(v.x); o.y = f2bf(v.y); o.z = f2bf(v.z); o.w = f2bf(v.w);
    ((ushort4*)xb)[i] = o;
  } else if (b < CASTB + HISTB) {
    int i = (b - CASTB) * 256 + threadIdx.x;
    if (i < ET) {
      int dst = (i < NEDGES) ? ei[NEDGES + i] : (i - NEDGES);
      atomicAdd(&deg[dst], 1);
    }
  } else {
    int bb = b - CASTB - HISTB;
    int which = bb >> 7, bx = bb & 127;
    const float* W;
    unsigned short* T;
    int K, N, noff;
    if (which == 0)      { W = W1l; T = w1t; K = 512; N = 256; noff = 0; }
    else if (which == 1) { W = W1r; T = w1t; K = 512; N = 256; noff = 256; }
    else if (which == 2) { W = W2l; T = w2t; K = 256; N = 512; noff = 0; }
    else                 { W = W2r; T = w2t; K = 256; N = 512; noff = 512; }
    int tpr = N >> 5;
    int tk = (bx / tpr) << 5;
    int tn = (bx % tpr) << 5;
    int c = threadIdx.x & 31, r = threadIdx.x >> 5;
#pragma unroll
    for (int rr = 0; rr < 32; rr += 8)
      tile[r + rr][c] = W[(size_t)(tk + r + rr) * N + tn + c];
    __syncthreads();
#pragma unroll
    for (int rr = 0; rr < 32; rr += 8)
      T[(size_t)(tn + r + rr + noff) * K + tk + c] = f2bf(tile[c][r + rr]);
  }
}

// ---------------- CSR scan/scatter ----------------

__global__ void k_scan1(const int* __restrict__ deg, int* __restrict__ part,
                        int* __restrict__ bsum, int n) {
  __shared__ int s[256];
  int tid = threadIdx.x;
  int i = blockIdx.x * 256 + tid;
  int v = (i < n) ? deg[i] : 0;
  s[tid] = v;
  __syncthreads();
  for (int off = 1; off < 256; off <<= 1) {
    int t = (tid >= off) ? s[tid - off] : 0;
    __syncthreads();
    s[tid] += t;
    __syncthreads();
  }
  if (i < n) part[i] = s[tid] - v;
  if (tid == 255) bsum[blockIdx.x] = s[255];
}

__global__ void k_scan2(int* bsum, int nb) {
  __shared__ int s[256];
  int t = threadIdx.x;
  int v = (t < nb) ? bsum[t] : 0;
  s[t] = v;
  __syncthreads();
  for (int off = 1; off < 256; off <<= 1) {
    int tv = (t >= off) ? s[t - off] : 0;
    __syncthreads();
    s[t] += tv;
    __syncthreads();
  }
  if (t < nb) bsum[t] = s[t] - v;
}

__global__ void k_scan3(const int* __restrict__ part, const int* __restrict__ bsum,
                        int* __restrict__ rowstart, int* __restrict__ cursor,
                        int n, int total) {
  int i = blockIdx.x * blockDim.x + threadIdx.x;
  if (i < n) {
    int v = part[i] + bsum[i >> 8];
    rowstart[i] = v;
    cursor[i] = v;
  }
  if (i == n) rowstart[n] = total;
}

__global__ void k_scatter(const int* __restrict__ ei, int* __restrict__ cursor,
                          int* __restrict__ csrsrc) {
  int i = blockIdx.x * blockDim.x + threadIdx.x;
  if (i >= ET) return;
  int src, dst;
  if (i < NEDGES) { src = ei[i]; dst = ei[NEDGES + i]; }
  else            { src = dst = i - NEDGES; }
  int pos = atomicAdd(&cursor[dst], 1);
  csrsrc[pos] = src;
}

// ---------------- bf16 MFMA GEMM, 3-buffer counted-vmcnt pipeline (T4) ----------

template <int N> __device__ __forceinline__ void waitvm() {
  if constexpr (N == 0) asm volatile("s_waitcnt vmcnt(0)" ::: "memory");
  else if constexpr (N == 4) asm volatile("s_waitcnt vmcnt(4)" ::: "memory");
  else asm volatile("s_waitcnt vmcnt(8)" ::: "memory");
}

__global__ __launch_bounds__(256) void k_gemm(
    const unsigned short* __restrict__ A, const unsigned short* __restrict__ Bt,
    const float* __restrict__ bL, const float* __restrict__ bR, int nsplit,
    unsigned short* __restrict__ C, int M, int K, int N) {
  __shared__ unsigned short As[3][128 * 32];
  __shared__ unsigned short Bs[3][128 * 32];
  int tid = threadIdx.x;
  int lane = tid & 63, wave = tid >> 6;
  int wr = (wave >> 1) * 64, wc = (wave & 1) * 64;
  int row0 = blockIdx.x * 128, col0 = blockIdx.y * 128;
  int fr = lane & 15, fq = lane >> 4;
  int sr = tid >> 2, sc = (tid & 3) * 8;

  const unsigned short* ga0 = &A[(size_t)(row0 + sr) * K + sc];
  const unsigned short* ga1 = &A[(size_t)(row0 + sr + 64) * K + sc];
  const unsigned short* gb0 = &Bt[(size_t)(col0 + sr) * K + sc];
  const unsigned short* gb1 = &Bt[(size_t)(col0 + sr + 64) * K + sc];

  f32x4 acc[4][4] = {};
  const int NT = K >> 5;

#define STAGE(b, k0)                                  \
  do {                                                \
    GLOAD16(ga0 + (k0), &As[b][tid * 8]);             \
    GLOAD16(ga1 + (k0), &As[b][2048 + tid * 8]);      \
    GLOAD16(gb0 + (k0), &Bs[b][tid * 8]);             \
    GLOAD16(gb1 + (k0), &Bs[b][2048 + tid * 8]);      \
  } while (0)

#define COMPUTE(b)                                                        \
  do {                                                                    \
    bf16x8 af[4], bfr[4];                                                 \
    _Pragma("unroll")                                                     \
    for (int m = 0; m < 4; ++m)                                           \
      af[m] = *(const bf16x8*)&As[b][(wr + m * 16 + fr) * 32 + fq * 8];   \
    _Pragma("unroll")                                                     \
    for (int n = 0; n < 4; ++n)                                           \
      bfr[n] = *(const bf16x8*)&Bs[b][(wc + n * 16 + fr) * 32 + fq * 8];  \
    _Pragma("unroll")                                                     \
    for (int m = 0; m < 4; ++m)                                           \
      _Pragma("unroll")                                                   \
      for (int n = 0; n < 4; ++n)                                         \
        acc[m][n] = __builtin_amdgcn_mfma_f32_16x16x32_bf16(af[m], bfr[n], acc[m][n], 0, 0, 0); \
  } while (0)

  STAGE(0, 0);
  STAGE(1, 32);
  STAGE(2, 64);

  for (int t = 0; t < NT - 3; ++t) {
    int b = t % 3;
    waitvm<8>();
    __builtin_amdgcn_s_barrier();
    COMPUTE(b);
    asm volatile("s_waitcnt lgkmcnt(0)" ::: "memory");
    __builtin_amdgcn_sched_barrier(0);
    __builtin_amdgcn_s_barrier();
    STAGE(b, (t + 3) << 5);
  }
  waitvm<8>(); __builtin_amdgcn_s_barrier(); COMPUTE((NT - 3) % 3);
  waitvm<4>(); __builtin_amdgcn_s_barrier(); COMPUTE((NT - 2) % 3);
  waitvm<0>(); __builtin_amdgcn_s_barrier(); COMPUTE((NT - 1) % 3);

#undef STAGE
#undef COMPUTE

#pragma unroll
  for (int m = 0; m < 4; ++m) {
#pragma unroll
    for (int n = 0; n < 4; ++n) {
      int col = col0 + wc + n * 16 + fr;
      float bv = (col < nsplit) ? bL[col] : bR[col - nsplit];
#pragma unroll
      for (int j = 0; j < 4; ++j) {
        int row = row0 + wr + m * 16 + fq * 4 + j;
        if (row < M) C[(size_t)row * N + col] = f2bf(acc[m][n][j] + bv);
      }
    }
  }
}

// ---------------- fused score + softmax + aggregate (R14 structure) --------------
// One wave per dst; 16 lanes/head; lane covers CHL=CQ*4 contiguous channels.
// Packed-f32 math; exp2-domain softmax, no max tracking (|p|<~15 by construction).

template <int CQ> struct raw_t;
template <> struct raw_t<1> { using T = uint2; };
template <> struct raw_t<2> { using T = uint4; };

template <int CQ>
__device__ __forceinline__ void unpackP(const typename raw_t<CQ>::T& r, f32x2v* x) {
  x[0] = cvtpair(r.x); x[1] = cvtpair(r.y);
  if constexpr (CQ == 2) { x[2] = cvtpair(r.z); x[3] = cvtpair(r.w); }
}

template <int CQ>
__device__ __forceinline__ float edge_score_pk(const f32x2v* x, const f32x2v* xr2,
                                               const f32x2v* att2) {
  const f32x2v c02 = {0.2f, 0.2f};
  f32x2v p2 = {0.f, 0.f};
#pragma unroll
  for (int j = 0; j < CQ * 2; ++j) {
    f32x2v s = x[j] + xr2[j];
    f32x2v g = VMAX(s, s * c02);
    p2 = VFMA(att2[j], g, p2);
  }
  return p2.x + p2.y;
}

template <int CQ, int MODE, int STR>
__global__ __launch_bounds__(256) void k_fused(
    const int* __restrict__ rowstart, const int* __restrict__ csrsrc,
    const unsigned short* __restrict__ xlr,
    const float* __restrict__ att, const float* __restrict__ bias,
    void* __restrict__ outp) {
  const int C = CQ * 64;
  const int CHL = CQ * 4;
  const int P = CQ * 2;
  using RawT = typename raw_t<CQ>::T;
  int dst = (blockIdx.x * blockDim.x + threadIdx.x) >> 6;
  int lane = threadIdx.x & 63;
  if (dst >= NNODES) return;
  int h = lane >> 4;
  int l = lane & 15;
  const int choff = h * C + l * CHL;

  f32x2v xr2[P], att2[P];
  {
    RawT xrr = *(const RawT*)&xlr[(size_t)dst * STR + STR / 2 + choff];
    unpackP<CQ>(xrr, xr2);
#pragma unroll
    for (int j = 0; j < P; ++j) {
      att2[j].x = att[choff + j * 2 + 0] * 1.44269504f;
      att2[j].y = att[choff + j * 2 + 1] * 1.44269504f;
    }
  }

  int rs = __builtin_amdgcn_readfirstlane(rowstart[dst]);
  int re = __builtin_amdgcn_readfirstlane(rowstart[dst + 1]);

  float den = 0.f;
  f32x2v acc2[P];
#pragma unroll
  for (int j = 0; j < P; ++j) acc2[j] = (f32x2v){0.f, 0.f};

  int i = rs;
  for (; i + 4 <= re; i += 4) {
    int s0 = csrsrc[i + 0];
    int s1 = csrsrc[i + 1];
    int s2 = csrsrc[i + 2];
    int s3 = csrsrc[i + 3];
    RawT r0 = *(const RawT*)&xlr[(unsigned)s0 * (unsigned)STR + choff];
    RawT r1 = *(const RawT*)&xlr[(unsigned)s1 * (unsigned)STR + choff];
    RawT r2 = *(const RawT*)&xlr[(unsigned)s2 * (unsigned)STR + choff];
    RawT r3 = *(const RawT*)&xlr[(unsigned)s3 * (unsigned)STR + choff];
    f32x2v x0[P], x1[P], x2[P], x3[P];
    unpackP<CQ>(r0, x0); unpackP<CQ>(r1, x1);
    unpackP<CQ>(r2, x2); unpackP<CQ>(r3, x3);
    float p0 = edge_score_pk<CQ>(x0, xr2, att2);
    float p1 = edge_score_pk<CQ>(x1, xr2, att2);
    float p2 = edge_score_pk<CQ>(x2, xr2, att2);
    float p3 = edge_score_pk<CQ>(x3, xr2, att2);
#pragma unroll
    for (int d = 1; d <= 8; d <<= 1) {
      p0 += __shfl_xor(p0, d);
      p1 += __shfl_xor(p1, d);
      p2 += __shfl_xor(p2, d);
      p3 += __shfl_xor(p3, d);
    }
    float w0 = EXP2F(p0), w1 = EXP2F(p1), w2 = EXP2F(p2), w3 = EXP2F(p3);
    den += (w0 + w1) + (w2 + w3);
    f32x2v w0v = {w0, w0}, w1v = {w1, w1}, w2v = {w2, w2}, w3v = {w3, w3};
#pragma unroll
    for (int j = 0; j < P; ++j) {
      f32x2v a = acc2[j];
      a = VFMA(w0v, x0[j], a);
      a = VFMA(w1v, x1[j], a);
      a = VFMA(w2v, x2[j], a);
      a = VFMA(w3v, x3[j], a);
      acc2[j] = a;
    }
  }
  for (; i < re; ++i) {
    int s0 = csrsrc[i];
    RawT r0 = *(const RawT*)&xlr[(unsigned)s0 * (unsigned)STR + choff];
    f32x2v x0[P];
    unpackP<CQ>(r0, x0);
    float p0 = edge_score_pk<CQ>(x0, xr2, att2);
#pragma unroll
    for (int d = 1; d <= 8; d <<= 1) p0 += __shfl_xor(p0, d);
    float w0 = EXP2F(p0);
    den += w0;
    f32x2v wv = {w0, w0};
#pragma unroll
    for (int j = 0; j < P; ++j) acc2[j] = VFMA(wv, x0[j], acc2[j]);
  }

  float inv = 1.f / (den + 1e-16f);

  if (MODE == 0) {
    unsigned short* out = (unsigned short*)outp;
#pragma unroll
    for (int q = 0; q < CQ; ++q) {
      const float4 bv = *(const float4*)&bias[choff + q * 4];
      ushort4 o;
      o.x = f2bf(fmaxf(acc2[q * 2 + 0].x * inv + bv.x, 0.f));
      o.y = f2bf(fmaxf(acc2[q * 2 + 0].y * inv + bv.y, 0.f));
      o.z = f2bf(fmaxf(acc2[q * 2 + 1].x * inv + bv.z, 0.f));
      o.w = f2bf(fmaxf(acc2[q * 2 + 1].y * inv + bv.w, 0.f));
      *(ushort4*)&out[(size_t)dst * (HEADS * C) + choff + q * 4] = o;
    }
  } else {
    float* out = (float*)outp;
    float rr[8];   // CHL <= 8
#pragma unroll
    for (int j = 0; j < P; ++j) {
      rr[j * 2 + 0] = acc2[j].x * inv;
      rr[j * 2 + 1] = acc2[j].y * inv;
    }
#pragma unroll
    for (int c = 0; c < CHL; ++c) {
      rr[c] += __shfl_xor(rr[c], 16);   // sum across heads
      rr[c] += __shfl_xor(rr[c], 32);
    }
    if (lane < 16) {
#pragma unroll
      for (int q = 0; q < CQ; ++q) {
        int c = lane * CHL + q * 4;
        float4 o;
        o.x = rr[q * 4 + 0] * 0.25f + bias[c + 0];
        o.y = rr[q * 4 + 1] * 0.25f + bias[c + 1];
        o.z = rr[q * 4 + 2] * 0.25f + bias[c + 2];
        o.w = rr[q * 4 + 3] * 0.25f + bias[c + 3];
        *(float4*)&out[(size_t)dst * C + c] = o;
      }
    }
  }
}

// ---------------- orchestration ----------------

extern "C" void kernel_launch(void* const* d_in, const int* in_sizes, int n_in,
                              void* d_out, int out_size, void* d_ws, size_t ws_size,
                              hipStream_t stream) {
  (void)in_sizes; (void)n_in; (void)out_size; (void)ws_size;
  const float* x     = (const float*)d_in[0];
  const int*   ei    = (const int*)d_in[1];
  const float* W1l   = (const float*)d_in[2];
  const float* b1l   = (const float*)d_in[3];
  const float* W1r   = (const float*)d_in[4];
  const float* b1r   = (const float*)d_in[5];
  const float* att1  = (const float*)d_in[6];
  const float* bias1 = (const float*)d_in[7];
  const float* W2l   = (const float*)d_in[8];
  const float* b2l   = (const float*)d_in[9];
  const float* W2r   = (const float*)d_in[10];
  const float* b2r   = (const float*)d_in[11];
  const float* att2  = (const float*)d_in[12];
  const float* bias2 = (const float*)d_in[13];
  float* out = (float*)d_out;

  char* ws = (char*)d_ws;
  size_t off = 0;
  auto alloc = [&](size_t bytes) {
    char* p = ws + off;
    off = (off + bytes + 255) & ~(size_t)255;
    return p;
  };
  int*  deg      = (int*)alloc((size_t)NNODES * 4);
  int*  part     = (int*)alloc((size_t)NNODES * 4);
  int*  bsum     = (int*)alloc(256 * 4);
  int*  rowstart = (int*)alloc((size_t)(NNODES + 1) * 4);
  int*  cursor   = (int*)alloc((size_t)NNODES * 4);
  int*  csrsrc   = (int*)alloc((size_t)(ET + 32) * 4);
  unsigned short* xb   = (unsigned short*)alloc((size_t)NNODES * 512 * 2);
  unsigned short* w1t  = (unsigned short*)alloc((size_t)512 * 512 * 2);
  unsigned short* w2t  = (unsigned short*)alloc((size_t)1024 * 256 * 2);
  unsigned short* xlr1 = (unsigned short*)alloc((size_t)NNODES * 512 * 2);
  unsigned short* hbuf = (unsigned short*)alloc((size_t)NNODES * 256 * 2);
  unsigned short* xlr2 = (unsigned short*)alloc((size_t)NNODES * 1024 * 2);
  (void)alloc(64 * 1024);   // tail pad for GEMM A-row overrun reads

  (void)hipMemsetAsync(deg, 0, (size_t)NNODES * 4, stream);

  // prep: cast x | histogram | weight transpose (merged)
  k_prep<<<PREPB, 256, 0, stream>>>(ei, deg, x, xb, W1l, W1r, W2l, W2r, w1t, w2t);

  int nb = (NNODES + 255) / 256;
  k_scan1<<<nb, 256, 0, stream>>>(deg, part, bsum, NNODES);
  k_scan2<<<1, 256, 0, stream>>>(bsum, nb);
  k_scan3<<<(NNODES + 256) / 256, 256, 0, stream>>>(part, bsum, rowstart, cursor, NNODES, ET);
  k_scatter<<<(ET + 255) / 256, 256, 0, stream>>>(ei, cursor, csrsrc);

  const int gridM = (NNODES + 127) / 128;   // 391
  const int gridFused = (NNODES + 3) / 4;   // 12500

  // Layer 1: combined [W1l|W1r], K=512, N=512
  k_gemm<<<dim3(gridM, 4), 256, 0, stream>>>(xb, w1t, b1l, b1r, 256, xlr1, NNODES, 512, 512);
  k_fused<1, 0, 512><<<gridFused, 256, 0, stream>>>(rowstart, csrsrc, xlr1, att1, bias1, hbuf);

  // Layer 2: combined [W2l|W2r], K=256, N=1024
  k_gemm<<<dim3(gridM, 8), 256, 0, stream>>>(hbuf, w2t, b2l, b2r, 512, xlr2, NNODES, 256, 1024);
  k_fused<2, 1, 1024><<<gridFused, 256, 0, stream>>>(rowstart, csrsrc, xlr2, att2, bias2, out);
}